// Round 5
// baseline (430.900 us; speedup 1.0000x reference)
//
#include <hip/hip_runtime.h>
#include <hip/hip_bf16.h>

// Conv2D 3x3 s1 p1: x[8,16,512,512] f32, w[16,144] f32 -> out[8,16,512,512] f32
//
// R8: LDS-FREE direct-MFMA conv (post R3-R7 ledger):
//   R3 (122us) = best staged variant; all pipes <40%, time = structural stall
//   (stage->barrier->compute convoy). R4/R7: >64 live VGPRs under big LDS =>
//   spills, not grants. R5: occupancy alone doesn't help. R6: d_ws => +81us
//   harness poison-fill. Conclusion: delete the staging phase instead of
//   hiding it.
//
//   B-fragments built directly from global: for K-step f, lane(quad,l15) needs
//   x[ci=(quad&1)*8+j][h+dh(tap)][w0+l15+dw(tap)], tap=f*2+(quad>>1) (f<4),
//   tap=8 (f=4; A=0 pads for quad>=2). 8 strided dword loads/lane, 4x64B
//   coalesced segments per instruction, L1/L2-hot (taps re-read rows 9x; HBM
//   sees only first touch). Deletes: staging, transpose, ds_write/read, halo
//   pass, ALL barriers, ALL LDS. Occupancy VGPR-bound only. Numerics identical
//   to R3 (same k-order k=tap*16+ci, same RNE cvt, same 5-MFMA accumulation).
//
//   Block = one (n,h) output row (4 waves x 128 px); per-16px-group wave-
//   uniform fast/slow path (slow only at image edges). XCD swizzle: n=bid&7,
//   h=bid>>3 -> h-adjacent rows time-adjacent on same XCD (L2 reuse of the
//   3-row window). Tripwires: WRITE_SIZE must stay ~131,090 KB (no spill);
//   VALUBusy should RISE (cvt/loads now the visible pipe).

#define IH 512
#define IW 512
#define CI 16
#define CO 16
#define PLANE (IH * IW)          // 262144 elems per (n,ci) plane

typedef short short8 __attribute__((ext_vector_type(8)));
typedef float f32x4  __attribute__((ext_vector_type(4)));

__device__ __forceinline__ short f32_to_bf16_bits(float v) {
    __hip_bfloat16 b = __float2bfloat16(v);   // RNE
    return __builtin_bit_cast(short, b);
}

// Build B-fragment: b[j] = bf16(x[cb+j][hh][ww]), 0 if (hh,ww) OOB.
// SAFE=true: caller guarantees in-bounds (interior fast path, no checks).
template<bool SAFE>
__device__ __forceinline__ short8 build_bfrag(const float* __restrict__ xn,
                                              int cb, int hh, int ww) {
    short8 b;
    if (SAFE) {
        const int base = cb * PLANE + hh * IW + ww;
#pragma unroll
        for (int j = 0; j < 8; ++j)
            b[j] = f32_to_bf16_bits(xn[base + j * PLANE]);
    } else {
        const bool ok = ((unsigned)hh < (unsigned)IH) && ((unsigned)ww < (unsigned)IW);
        const int hc = ok ? hh : 0;           // clamped safe address
        const int wc = ok ? ww : 0;
        const int base = cb * PLANE + hc * IW + wc;
#pragma unroll
        for (int j = 0; j < 8; ++j) {
            const float v = xn[base + j * PLANE];
            b[j] = ok ? f32_to_bf16_bits(v) : (short)0;
        }
    }
    return b;
}

__global__ __launch_bounds__(256, 6)
void conv3x3_direct(const float* __restrict__ x, const float* __restrict__ wgt,
                    float* __restrict__ out) {
    const int tid  = threadIdx.x;
    const int wave = tid >> 6;
    const int lane = tid & 63;
    const int quad = lane >> 4;
    const int l15  = lane & 15;

    // XCD swizzle: n = bid&7 (one image per XCD under round-robin),
    // h = bid>>3 -> consecutive rows on the same XCD share the 3-row window.
    const int bid = blockIdx.x;
    const int n   = bid & 7;
    const int h   = bid >> 3;

    const float* xn = x + (size_t)n * CI * PLANE;

    // ---- A fragments: W[co=l15][k], k = f*32 + quad*8 + j; zero for k>=144 ----
    short8 afrag[5];
#pragma unroll
    for (int f = 0; f < 5; ++f) {
#pragma unroll
        for (int j = 0; j < 8; ++j) {
            const int k = f * 32 + quad * 8 + j;
            float val = 0.0f;
            if (k < 144) {
                const int ci  = k & 15;
                const int tap = k >> 4;
                val = wgt[l15 * 144 + ci * 9 + tap];
            }
            afrag[f][j] = f32_to_bf16_bits(val);
        }
    }

    // ---- per-f tap deltas (depend only on quad) ----
    const int cb = (quad & 1) * 8;            // ci base for this lane's k-slots
    int dh_[5], dw_[5];
#pragma unroll
    for (int f = 0; f < 5; ++f) {
        const int tap = (f < 4) ? (f * 2 + (quad >> 1)) : 8;
        dh_[f] = tap / 3 - 1;
        dw_[f] = tap - (tap / 3) * 3 - 1;
    }

    const bool hedge = (h == 0) || (h == IH - 1);
    float* on = out + (size_t)n * CO * PLANE + h * IW;

    // ---- 8 groups of 16 px per wave; 5 MFMA K-steps per group ----
#pragma unroll 2
    for (int g = 0; g < 8; ++g) {
        const int px0 = wave * 128 + g * 16;
        // safe: all lanes' (hh,ww) in-bounds for every tap
        const bool safe = !hedge && (px0 >= 16) && (px0 <= 480);

        f32x4 acc = (f32x4){0.f, 0.f, 0.f, 0.f};
        if (safe) {
#pragma unroll
            for (int f = 0; f < 5; ++f) {
                const short8 b = build_bfrag<true>(xn, cb, h + dh_[f], px0 + l15 + dw_[f]);
                acc = __builtin_amdgcn_mfma_f32_16x16x32_bf16(afrag[f], b, acc, 0, 0, 0);
            }
        } else {
#pragma unroll
            for (int f = 0; f < 5; ++f) {
                const short8 b = build_bfrag<false>(xn, cb, h + dh_[f], px0 + l15 + dw_[f]);
                acc = __builtin_amdgcn_mfma_f32_16x16x32_bf16(afrag[f], b, acc, 0, 0, 0);
            }
        }

        // store: C/D col = l15 = pixel, row = quad*4+reg = co
        const int gw = px0 + l15;
#pragma unroll
        for (int reg = 0; reg < 4; ++reg) {
            const int co = quad * 4 + reg;
            on[(size_t)co * PLANE + gw] = acc[reg];
        }
    }
}

extern "C" void kernel_launch(void* const* d_in, const int* in_sizes, int n_in,
                              void* d_out, int out_size, void* d_ws, size_t ws_size,
                              hipStream_t stream) {
    const float* x = (const float*)d_in[0];
    const float* w = (const float*)d_in[1];
    float* out     = (float*)d_out;

    dim3 grid(8 * IH);   // 4096 blocks: n = bid&7, h = bid>>3
    dim3 block(256);     // 4 waves x 128 px = one 512-px output row
    conv3x3_direct<<<grid, block, 0, stream>>>(x, w, out);
}

// Round 6
// 320.072 us; speedup vs baseline: 1.3463x; 1.3463x over previous
//
#include <hip/hip_runtime.h>
#include <hip/hip_bf16.h>

// Conv2D 3x3 s1 p1: x[8,16,512,512] f32, w[16,144] f32 -> out[8,16,512,512] f32
//
// R9: transpose-in-the-gather via global_load_lds size=4.
//   Ledger: R0 122us (staging serialized: ~5 exposed HBM roundtrips/thread);
//   R4/R7: compiler spills instead of granting staging ILP; R5: occupancy
//   alone no help; R6: d_ws => 512MiB poison fill; R8: no-LDS direct 258us.
//   The only untried mechanism: fire-and-forget staging. global_load_lds
//   uses NO VGPRs and NO VALU per element -> allocator can't serialize it.
//   Its LDS dest is linear (base+lane*4) but the GLOBAL source is per-lane,
//   so the lane->(ci,px) mapping performs the NCHW->channels-last transpose
//   inside the gather. 72 async issues/thread, one barrier drain. Each wave
//   instr touches 16x16B global segments == same segment count as ideal
//   dwordx4 staging.
//
//   LDS: channels-last f32 [18][px' 0..65][16ci] = 76,032B -> 2 blocks/CU.
//   Bank swizzle (window-local, 4px=16-slot windows): phys_slot = ls ^ (px&7)
//   -> stride-64B ds_read_b128 fragment reads are ~2-way (free). Inverse of
//   the swizzle is baked into the per-thread staging source decode.
//   Fragment = 2x ds_read_b128 + 8 RNE cvts; all addr terms hoisted per-f.
//   Numerics bit-identical to R0. OOB rows: clamped source + block-uniform
//   zero-pass (edge blocks only). Halo cols px=-1/64: masked scatter pass,
//   stored unswizzled in px'=0/65 slots (read side: swz operand = 0 there).
//   XCD swizzle kept: n = bid&7, bx fastest.

#define IH 512
#define IW 512
#define CI 16
#define CO 16
#define TH 16
#define TW 64
#define LROWS 18
#define ROWB 4224            // 66 px * 64 B per LDS row
#define LDSB (LROWS * ROWB)  // 76,032 B
#define PLANE (IH * IW)

typedef short short8 __attribute__((ext_vector_type(8)));
typedef float f32x4  __attribute__((ext_vector_type(4)));
typedef int   i32x4  __attribute__((ext_vector_type(4)));

__device__ __forceinline__ short f32_to_bf16_bits(float v) {
    __hip_bfloat16 b = __float2bfloat16(v);   // RNE
    return __builtin_bit_cast(short, b);
}

__device__ __forceinline__ void gload_lds4(const void* g, void* l) {
    __builtin_amdgcn_global_load_lds(
        (const __attribute__((address_space(1))) void*)g,
        (__attribute__((address_space(3))) void*)l, 4, 0, 0);
}

__global__ __launch_bounds__(256, 2)
void conv3x3_glds(const float* __restrict__ x, const float* __restrict__ wgt,
                  float* __restrict__ out) {
    __shared__ char lds[LDSB];

    const int tid  = threadIdx.x;
    const int wv   = tid >> 6;
    const int lane = tid & 63;
    const int quad = lane >> 4;
    const int l15  = lane & 15;

    // XCD swizzle: image = bid&7 (one image per XCD), bx fastest, then by
    const int bid   = blockIdx.x;
    const int n     = bid & 7;
    const int t     = bid >> 3;
    const int wbase = (t & 7) * TW;      // 8 tiles in x
    const int hbase = (t >> 3) * TH;     // 32 tiles in y

    const float* xn = x + (size_t)n * CI * PLANE;

    // ===== staging decode: invert the window-local swizzle ps = ls ^ (p&7) =====
    // Wave writes 256B = one 4-px window; p0 = k2*16 + wv*4 (tile coords).
    // thread: slot = (tid>>2)&15, dword = tid&3; a = px-in-window, b = ci-group.
    const int slot  = (tid >> 2) & 15;
    const int dword = tid & 3;
    const int a1 = (slot >> 3) & 1;
    const int a0 = ((slot >> 2) & 1) ^ (wv & 1);   // p0b2 = wv&1
    const int b1 = ((slot >> 1) & 1) ^ a1;
    const int b0 = (slot & 1) ^ a0;
    const int a  = a0 + 2 * a1;
    const int b  = b0 + 2 * b1;
    const int sci = 4 * b + dword;
    const int colbase = wbase + wv * 4 + a;        // + k2*16 per sub-round

    const char* gthread = (const char*)(xn + (size_t)sci * PLANE + colbase);
    char* lthread = lds + 64 + wv * 256;           // px'=1 base, this wave's window

    // ===== halo col loads (issued first; writes after the async stream) =====
    float hval[3];
    int   hoff[3];
    bool  hact[3];
#pragma unroll
    for (int rep = 0; rep < 3; ++rep) {
        const int i   = rep * 256 + tid;
        const bool act = (rep < 2) || (tid < 64);   // 576 items total
        const int idx = act ? i : 0;
        const int row  = idx >> 5;
        const int col2 = (idx >> 4) & 1;
        const int hci  = idx & 15;
        const int gh = hbase - 1 + row;
        const int gw = wbase - 1 + col2 * 65;
        const bool ok = act && ((unsigned)gh < (unsigned)IH) && ((unsigned)gw < (unsigned)IW);
        hval[rep] = ok ? xn[(size_t)hci * PLANE + (size_t)(ok ? gh : 0) * IW + (ok ? gw : 0)] : 0.0f;
        hoff[rep] = row * ROWB + col2 * (65 * 64) + hci * 4;   // unswizzled halo slots
        hact[rep] = act;
    }

    // ===== interior async staging: 72 fire-and-forget gload_lds4 =====
#pragma unroll
    for (int rr = 0; rr < LROWS; ++rr) {
        const int gh   = hbase - 1 + rr;
        const int srow = gh < 0 ? 0 : (gh > IH - 1 ? IH - 1 : gh);  // clamp; zero-pass fixes
        const char* gr = gthread + (size_t)srow * (IW * 4);
        char* lr = lthread + rr * ROWB;
#pragma unroll
        for (int k2 = 0; k2 < 4; ++k2)
            gload_lds4(gr + k2 * 64, lr + k2 * 1024);
    }

    // ===== A fragments in the load shadow: W[co=l15][k], k=f*32+quad*8+j =====
    short8 afrag[5];
#pragma unroll
    for (int f = 0; f < 5; ++f) {
#pragma unroll
        for (int j = 0; j < 8; ++j) {
            const int k = f * 32 + quad * 8 + j;
            float val = 0.0f;
            if (k < 144) {
                const int ci  = k & 15;
                const int tap = k >> 4;
                val = wgt[l15 * 144 + ci * 9 + tap];
            }
            afrag[f][j] = f32_to_bf16_bits(val);
        }
    }

    // halo ds_writes (compiler waits only on the halo loads)
#pragma unroll
    for (int rep = 0; rep < 3; ++rep)
        if (hact[rep]) *(float*)(lds + hoff[rep]) = hval[rep];

    __syncthreads();   // drains vmcnt (all gload_lds) + lgkm

    // ===== zero-pass for OOB rows (block-uniform, edge blocks only) =====
    if (hbase == 0 || hbase == (IH - TH)) {
        const int zr = (hbase == 0) ? 0 : (LROWS - 1);
        char* zb = lds + zr * ROWB;
        *(i32x4*)(zb + tid * 16) = (i32x4){0, 0, 0, 0};
        if (tid < 8) *(i32x4*)(zb + 4096 + tid * 16) = (i32x4){0, 0, 0, 0};
        __syncthreads();
    }

    // ===== per-f read-address bases (all hoisted) =====
    // addr(r,c4s,f) = Cf + r*ROWB + c4s*1024 ; second half = addr ^ 16
    // Cf = (wv*4+1+dh)*ROWB + (lw&~3)*64 + 64 + (phys_slot_A)*16,
    //   phys_slot_A = (2q ^ (lw&3)) | ((lw0^lw2)<<2) | (lw1<<3), lw = l15+dw.
    // c4s==0 & lw<0 -> halo px=-1: Cf0 = rowterm + q*32 (unswizzled).
    const int q = quad & 1;
    int Cf_in[5], Cf_0[5];
#pragma unroll
    for (int f = 0; f < 5; ++f) {
        const int tap = (f < 4) ? (f * 2 + (quad >> 1)) : 8;
        const int dh  = tap / 3 - 1;
        const int dw  = tap - (tap / 3) * 3 - 1;
        const int lw  = l15 + dw;                    // -1 .. 16
        const int Rf  = (wv * 4 + 1 + dh) * ROWB;
        const int lw0 = lw & 1, lw1 = (lw >> 1) & 1, lw2 = (lw >> 2) & 1;
        const int slotA = ((2 * q) ^ (lw & 3)) | ((lw0 ^ lw2) << 2) | (lw1 << 3);
        Cf_in[f] = Rf + (lw & ~3) * 64 + 64 + slotA * 16;
        Cf_0[f]  = (lw < 0) ? (Rf + q * 32) : Cf_in[f];
    }

    // ===== MFMA main: 4 c4-segments x 4 rows x 5 K-steps =====
    f32x4 acc[4][4];
#pragma unroll
    for (int r = 0; r < 4; ++r)
#pragma unroll
        for (int c4 = 0; c4 < 4; ++c4)
            acc[r][c4] = (f32x4){0.f, 0.f, 0.f, 0.f};

#pragma unroll
    for (int c4s = 0; c4s < 4; ++c4s) {
#pragma unroll
        for (int r = 0; r < 4; ++r) {
#pragma unroll
            for (int f = 0; f < 5; ++f) {
                const int basef = (c4s == 0 ? Cf_0[f] : Cf_in[f]) + r * ROWB + c4s * 1024;
                const f32x4 lo = *(const f32x4*)(lds + basef);          // ci q*8..+3
                const f32x4 hi = *(const f32x4*)(lds + (basef ^ 16));   // ci q*8+4..+7
                short8 bfrag;
#pragma unroll
                for (int j = 0; j < 4; ++j) {
                    bfrag[j]     = f32_to_bf16_bits(lo[j]);
                    bfrag[j + 4] = f32_to_bf16_bits(hi[j]);
                }
                acc[r][c4s] = __builtin_amdgcn_mfma_f32_16x16x32_bf16(afrag[f], bfrag, acc[r][c4s], 0, 0, 0);
            }
        }
    }

    // ===== store: C/D col = l15 = pixel, row = quad*4+reg = co =====
    float* on = out + (size_t)n * CO * PLANE;
#pragma unroll
    for (int r = 0; r < 4; ++r) {
        const int gh = hbase + wv * 4 + r;
#pragma unroll
        for (int c4 = 0; c4 < 4; ++c4) {
            const int gw = wbase + c4 * 16 + l15;
#pragma unroll
            for (int reg = 0; reg < 4; ++reg) {
                const int co = quad * 4 + reg;
                on[((size_t)co * IH + gh) * IW + gw] = acc[r][c4][reg];
            }
        }
    }
}

extern "C" void kernel_launch(void* const* d_in, const int* in_sizes, int n_in,
                              void* d_out, int out_size, void* d_ws, size_t ws_size,
                              hipStream_t stream) {
    const float* x = (const float*)d_in[0];
    const float* w = (const float*)d_in[1];
    float* out     = (float*)d_out;

    dim3 grid((IW / TW) * (IH / TH) * 8);   // 8*32*8 = 2048 blocks, 1D swizzled
    dim3 block(256);
    conv3x3_glds<<<grid, block, 0, stream>>>(x, w, out);
}